// Round 2
// baseline (703.926 us; speedup 1.0000x reference)
//
#include <hip/hip_runtime.h>

// GQA forward on MI355X. bf16 MFMA everywhere, f32 accum.
// H=16 heads, G=4 groups, D=2048, HD=128, KV=512, bs=2, s=2048.
// NOTE: reference's _expand_kv is a RAW RESHAPE (scramble), not a transpose:
//   k[b,h,t',d] = Kp[b, h*128 + t'/16, (t'%4)*128 + d]   (same for v)
//
// R2 change: __launch_bounds__(256,2) on gemm_bt / attn_fwd. R1 compiled them
// without bounds -> 64-VGPR cap -> scratch spills (attn WRITE_SIZE 534MB vs
// 16MB of real output). This is the spill fix; everything else unchanged.

#define DEV __device__ __forceinline__

typedef float f32x4 __attribute__((ext_vector_type(4)));
typedef __bf16 bf16x8 __attribute__((ext_vector_type(8)));

DEV f32x4 mfma16(bf16x8 a, bf16x8 b, f32x4 c) {
  return __builtin_amdgcn_mfma_f32_16x16x32_bf16(a, b, c, 0, 0, 0);
}

// async global->LDS, 16B per lane. LDS dest = wave-uniform base + lane*16.
DEV void gld16(void* gsrc, void* ldst) {
  __builtin_amdgcn_global_load_lds(
      (__attribute__((address_space(1))) unsigned int*)gsrc,
      (__attribute__((address_space(3))) unsigned int*)ldst, 16, 0, 0);
}

// ---------------- X f32 -> bf16 ----------------
__global__ void convert_f32_bf16(const float* __restrict__ in, __bf16* __restrict__ out) {
  size_t i = ((size_t)blockIdx.x * 256 + threadIdx.x) * 8;
  float4 a = *(const float4*)(in + i);
  float4 b = *(const float4*)(in + i + 4);
  bf16x8 v;
  v[0] = (__bf16)a.x; v[1] = (__bf16)a.y; v[2] = (__bf16)a.z; v[3] = (__bf16)a.w;
  v[4] = (__bf16)b.x; v[5] = (__bf16)b.y; v[6] = (__bf16)b.z; v[7] = (__bf16)b.w;
  *(bf16x8*)(out + i) = v;
}

// ---------------- W [K][N] f32 -> WT [N][K] bf16 ----------------
__global__ void transpose_w_bf16(const float* __restrict__ W, __bf16* __restrict__ WT,
                                 int K, int N) {
  __shared__ float t[32][33];
  int tx = threadIdx.x & 31, ty = threadIdx.x >> 5;  // 32x8
  int n0 = blockIdx.x * 32, k0 = blockIdx.y * 32;
#pragma unroll
  for (int i = 0; i < 4; i++)
    t[ty + i * 8][tx] = W[(size_t)(k0 + ty + i * 8) * N + n0 + tx];
  __syncthreads();
#pragma unroll
  for (int i = 0; i < 4; i++)
    WT[(size_t)(n0 + ty + i * 8) * K + k0 + tx] = (__bf16)t[tx][ty + i * 8];
}

// ---------------- GEMM: C[M][N] = A[M][K] * Bt[N][K]^T + bias, m97 structure ----------------
template <int F32OUT>
__global__ __launch_bounds__(256, 2)
void gemm_bt(const __bf16* __restrict__ A, const __bf16* __restrict__ Bt,
             const float* __restrict__ bias, float scale, void* __restrict__ Cout,
             int M, int N, int K) {
  __shared__ __bf16 As[128 * 32];
  __shared__ __bf16 Bs[128 * 32];
  int tid = threadIdx.x, lane = tid & 63, w = tid >> 6;
  int wm = w >> 1, wn = w & 1, lg = lane >> 4, lc = lane & 15;
  int m0 = blockIdx.y * 128, n0 = blockIdx.x * 128;
  int srow = w * 16 + (lane >> 2), scol = (lane & 3) * 8;  // stage: 16B/lane
  const __bf16* Ag = A + (size_t)(m0 + srow) * K + scol;
  const __bf16* Bg = Bt + (size_t)(n0 + srow) * K + scol;
  f32x4 acc[4][4] = {};
  int nk = K >> 5;
  for (int kt = 0; kt < nk; ++kt) {
    if (kt) __syncthreads();
    const __bf16* a = Ag + kt * 32;
    const __bf16* bp = Bg + kt * 32;
    gld16((void*)a, As + (w * 16) * 32);
    gld16((void*)(a + (size_t)64 * K), As + (64 + w * 16) * 32);
    gld16((void*)bp, Bs + (w * 16) * 32);
    gld16((void*)(bp + (size_t)64 * K), Bs + (64 + w * 16) * 32);
    __syncthreads();
    bf16x8 af[4], bf[4];
#pragma unroll
    for (int i = 0; i < 4; i++)
      af[i] = *(const bf16x8*)(As + (wm * 64 + i * 16 + lc) * 32 + lg * 8);
#pragma unroll
    for (int i = 0; i < 4; i++)
      bf[i] = *(const bf16x8*)(Bs + (wn * 64 + i * 16 + lc) * 32 + lg * 8);
#pragma unroll
    for (int mi = 0; mi < 4; mi++)
#pragma unroll
      for (int ni = 0; ni < 4; ni++)
        acc[mi][ni] = mfma16(af[mi], bf[ni], acc[mi][ni]);
  }
  float bcol[4];
#pragma unroll
  for (int ni = 0; ni < 4; ni++) bcol[ni] = bias[n0 + wn * 64 + ni * 16 + lc];
#pragma unroll
  for (int mi = 0; mi < 4; mi++)
#pragma unroll
    for (int ni = 0; ni < 4; ni++)
#pragma unroll
      for (int r = 0; r < 4; r++) {
        int row = m0 + wm * 64 + mi * 16 + lg * 4 + r;
        int col = n0 + wn * 64 + ni * 16 + lc;
        float v = (acc[mi][ni][r] + bcol[ni]) * scale;
        if (F32OUT)
          ((float*)Cout)[(size_t)row * N + col] = v;
        else
          ((__bf16*)Cout)[(size_t)row * N + col] = (__bf16)v;
      }
}

// ---------------- expand/scramble KV ----------------
// Kx[bh][t'][d] = Kp[b*2048 + h*128 + t'/16][(t'%4)*128 + d]
// Vxt[bh][d][t'] = Vp[ same row ][(t'%4)*128 + d]   (transposed for PV B-frags)
__global__ void expand_kv(const __bf16* __restrict__ Kp, const __bf16* __restrict__ Vp,
                          __bf16* __restrict__ Kx, __bf16* __restrict__ Vxt) {
  __shared__ __bf16 Kl[16][512];
  __shared__ __bf16 Vl[16][512];
  int tid = threadIdx.x;
  int bh = blockIdx.x >> 3, tc = blockIdx.x & 7;
  int b = bh >> 4, h = bh & 15;
  size_t srow0 = (size_t)b * 2048 + h * 128 + tc * 16;
#pragma unroll
  for (int it = 0; it < 4; ++it) {
    int idx = it * 256 + tid;
    int rr = idx >> 6, ch = idx & 63;
    *(float4*)(&Kl[rr][ch * 8]) = *(const float4*)(Kp + (srow0 + rr) * 512 + ch * 8);
    *(float4*)(&Vl[rr][ch * 8]) = *(const float4*)(Vp + (srow0 + rr) * 512 + ch * 8);
  }
  __syncthreads();
#pragma unroll
  for (int it = 0; it < 16; ++it) {  // Kx: 256 t' x 128 d
    int idx = it * 256 + tid;
    int tloc = idx >> 4, ch = idx & 15;
    int tp = tc * 256 + tloc, rr = tloc >> 4, g = tloc & 3;
    *(float4*)(Kx + ((size_t)bh * 2048 + tp) * 128 + ch * 8) =
        *(const float4*)(&Kl[rr][g * 128 + ch * 8]);
  }
#pragma unroll
  for (int it = 0; it < 16; ++it) {  // Vxt: 128 d x 256 t'
    int idx = it * 256 + tid;
    int d = idx >> 5, c8 = idx & 31;
    int rr = c8 >> 1;
    bf16x8 v;
#pragma unroll
    for (int j = 0; j < 8; j++) v[j] = Vl[rr][(j & 3) * 128 + d];
    *(bf16x8*)(Vxt + ((size_t)bh * 128 + d) * 2048 + tc * 256 + c8 * 8) = v;
  }
}

// ---------------- flash attention, causal ----------------
// block = 4 waves, QBLK=64 (16 q-rows/wave), KVBLK=64, HD=128.
// Q pre-scaled by log2e/sqrt(128); softmax in exp2 domain.
__global__ __launch_bounds__(256, 2)
void attn_fwd(const __bf16* __restrict__ Qb, const __bf16* __restrict__ Kx,
              const __bf16* __restrict__ Vxt, __bf16* __restrict__ attO) {
  __shared__ alignas(16) char Ks[64 * 256];    // [t'][256B], 16B blocks XOR-swizzled
  __shared__ alignas(16) char Vts[128 * 128];  // [d][128B]
  __shared__ alignas(16) char Ps[4 * 2048];    // per-wave P [16 q][64 t'] bf16
  int tid = threadIdx.x, lane = tid & 63, w = tid >> 6;
  int lg = lane >> 4, lc = lane & 15;
  int qt = 31 - (int)blockIdx.x;  // heavy blocks first
  int bh = blockIdx.y, b = bh >> 4, h = bh & 15;
  int q0 = qt * 64;
  const __bf16* Qrow = Qb + (size_t)(b * 2048 + q0 + w * 16 + lc) * 2048 + h * 128 + lg * 8;
  bf16x8 qf[4];
#pragma unroll
  for (int ks = 0; ks < 4; ks++) qf[ks] = *(const bf16x8*)(Qrow + ks * 32);
  f32x4 o[8] = {};
  float mrow[4], lrow[4];
#pragma unroll
  for (int r = 0; r < 4; r++) { mrow[r] = -3.0e38f; lrow[r] = 0.f; }
  const __bf16* Kg = Kx + (size_t)bh * 2048 * 128;
  const __bf16* Vg = Vxt + (size_t)bh * 128 * 2048;
  char* Psw = Ps + w * 2048;

  for (int kt = 0; kt <= qt; ++kt) {
    float4 kreg[4], vreg[4];
#pragma unroll
    for (int it = 0; it < 4; it++) {
      int idx = it * 256 + tid, kr = idx >> 4, kc = idx & 15;
      kreg[it] = *(const float4*)(Kg + (size_t)(kt * 64 + kr) * 128 + kc * 8);
    }
#pragma unroll
    for (int it = 0; it < 4; it++) {
      int idx = it * 256 + tid, vr = idx >> 3, vc = idx & 7;
      vreg[it] = *(const float4*)(Vg + (size_t)vr * 2048 + kt * 64 + vc * 8);
    }
    if (kt) __syncthreads();  // prev tile's LDS reads done before overwrite
#pragma unroll
    for (int it = 0; it < 4; it++) {
      int idx = it * 256 + tid, kr = idx >> 4, kc = idx & 15;
      *(float4*)(Ks + kr * 256 + ((kc * 16) ^ ((kr & 7) << 4))) = kreg[it];
    }
#pragma unroll
    for (int it = 0; it < 4; it++) {
      int idx = it * 256 + tid, vr = idx >> 3, vc = idx & 7;
      *(float4*)(Vts + vr * 128 + ((vc * 16) ^ ((vr & 7) << 4))) = vreg[it];
    }
    __syncthreads();

    // QK^T: S[16q][64t']
    f32x4 s[4];
#pragma unroll
    for (int nt = 0; nt < 4; nt++) {
      s[nt] = (f32x4){0.f, 0.f, 0.f, 0.f};
#pragma unroll
      for (int ks = 0; ks < 4; ks++) {
        int trow = nt * 16 + lc;
        bf16x8 kf = *(const bf16x8*)(Ks + trow * 256 + ((ks * 64 + lg * 16) ^ ((trow & 7) << 4)));
        s[nt] = mfma16(qf[ks], kf, s[nt]);
      }
    }
    if (kt == qt) {  // causal mask on diagonal tile
#pragma unroll
      for (int nt = 0; nt < 4; nt++)
#pragma unroll
        for (int r = 0; r < 4; r++)
          if (nt * 16 + lc > w * 16 + lg * 4 + r) s[nt][r] = -3.0e38f;
    }
    // online softmax (rows live on 16-lane groups; reduce via shfl_xor 1,2,4,8)
#pragma unroll
    for (int r = 0; r < 4; r++) {
      float v = fmaxf(fmaxf(s[0][r], s[1][r]), fmaxf(s[2][r], s[3][r]));
      v = fmaxf(v, __shfl_xor(v, 1));
      v = fmaxf(v, __shfl_xor(v, 2));
      v = fmaxf(v, __shfl_xor(v, 4));
      v = fmaxf(v, __shfl_xor(v, 8));
      float mn = fmaxf(mrow[r], v);
      float sc = exp2f(mrow[r] - mn);
      mrow[r] = mn;
      lrow[r] *= sc;
#pragma unroll
      for (int dt = 0; dt < 8; dt++) o[dt][r] *= sc;
      float rs = 0.f;
#pragma unroll
      for (int nt = 0; nt < 4; nt++) {
        float p = exp2f(s[nt][r] - mn);
        s[nt][r] = p;
        rs += p;
      }
      rs += __shfl_xor(rs, 1);
      rs += __shfl_xor(rs, 2);
      rs += __shfl_xor(rs, 4);
      rs += __shfl_xor(rs, 8);
      lrow[r] += rs;
    }
    // P (C-layout) -> per-wave LDS, bf16, swizzled; then consumed as A-frags
#pragma unroll
    for (int nt = 0; nt < 4; nt++)
#pragma unroll
      for (int r = 0; r < 4; r++) {
        int row = lg * 4 + r, col = nt * 16 + lc;
        *(__bf16*)(Psw + row * 128 + ((((col >> 3) << 4) ^ ((row & 7) << 4)) | ((col & 7) << 1))) =
            (__bf16)s[nt][r];
      }
    asm volatile("" ::: "memory");  // keep P-writes before PV reads (TBAA guard)
    // PV: o[16q][128d] += P[16q][64t'] * Vt
#pragma unroll
    for (int dt = 0; dt < 8; dt++) {
#pragma unroll
      for (int ks = 0; ks < 2; ks++) {
        bf16x8 af = *(const bf16x8*)(Psw + lc * 128 + ((ks * 64 + lg * 16) ^ ((lc & 7) << 4)));
        int vrow = dt * 16 + lc;
        bf16x8 vf = *(const bf16x8*)(Vts + vrow * 128 + ((ks * 64 + lg * 16) ^ ((vrow & 7) << 4)));
        o[dt] = mfma16(af, vf, o[dt]);
      }
    }
  }
  // epilogue: divide by l, store bf16 to attO[b*2048+q][h*128+d]
#pragma unroll
  for (int r = 0; r < 4; r++) {
    float inv = 1.0f / lrow[r];
    int row = b * 2048 + q0 + w * 16 + lg * 4 + r;
#pragma unroll
    for (int dt = 0; dt < 8; dt++)
      attO[(size_t)row * 2048 + h * 128 + dt * 16 + lc] = (__bf16)(o[dt][r] * inv);
  }
}

extern "C" void kernel_launch(void* const* d_in, const int* in_sizes, int n_in,
                              void* d_out, int out_size, void* d_ws, size_t ws_size,
                              hipStream_t stream) {
  const float* X = (const float*)d_in[0];
  const float* Wq = (const float*)d_in[1];
  const float* bq = (const float*)d_in[2];
  const float* Wk = (const float*)d_in[3];
  const float* bk = (const float*)d_in[4];
  const float* Wv = (const float*)d_in[5];
  const float* bv = (const float*)d_in[6];
  const float* Wo = (const float*)d_in[7];
  const float* bo = (const float*)d_in[8];
  char* ws = (char*)d_ws;
  const size_t MB = 1024 * 1024;
  __bf16* Xb  = (__bf16*)(ws + 0);        // 16 MB
  __bf16* WqT = (__bf16*)(ws + 16 * MB);  // 8 MB
  __bf16* WkT = (__bf16*)(ws + 24 * MB);  // 2 MB
  __bf16* WvT = (__bf16*)(ws + 27 * MB);  // 2 MB
  __bf16* WoT = (__bf16*)(ws + 30 * MB);  // 8 MB
  __bf16* Qbf = (__bf16*)(ws + 38 * MB);  // 16 MB
  __bf16* Kp  = (__bf16*)(ws + 54 * MB);  // 4 MB
  __bf16* Vp  = (__bf16*)(ws + 58 * MB);  // 4 MB
  __bf16* Kx  = (__bf16*)(ws + 62 * MB);  // 16 MB
  __bf16* Vxt = (__bf16*)(ws + 78 * MB);  // 16 MB
  __bf16* aO  = (__bf16*)(ws + 94 * MB);  // 16 MB -> 110 MB total

  convert_f32_bf16<<<4096, 256, 0, stream>>>(X, Xb);
  transpose_w_bf16<<<dim3(64, 64), 256, 0, stream>>>(Wq, WqT, 2048, 2048);
  transpose_w_bf16<<<dim3(16, 64), 256, 0, stream>>>(Wk, WkT, 2048, 512);
  transpose_w_bf16<<<dim3(16, 64), 256, 0, stream>>>(Wv, WvT, 2048, 512);
  transpose_w_bf16<<<dim3(64, 64), 256, 0, stream>>>(Wo, WoT, 2048, 2048);

  // fold 1/sqrt(HD) * log2(e) into Q so softmax uses exp2 directly
  float qscale = 1.4426950408889634f * 0.08838834764831845f;
  gemm_bt<0><<<dim3(16, 32), 256, 0, stream>>>(Xb, WqT, bq, qscale, Qbf, 4096, 2048, 2048);
  gemm_bt<0><<<dim3(4, 32), 256, 0, stream>>>(Xb, WkT, bk, 1.0f, Kp, 4096, 512, 2048);
  gemm_bt<0><<<dim3(4, 32), 256, 0, stream>>>(Xb, WvT, bv, 1.0f, Vp, 4096, 512, 2048);

  expand_kv<<<256, 256, 0, stream>>>(Kp, Vp, Kx, Vxt);
  attn_fwd<<<dim3(32, 32), 256, 0, stream>>>(Qbf, Kx, Vxt, aO);

  gemm_bt<1><<<dim3(16, 32), 256, 0, stream>>>(aO, WoT, bo, 1.0f, (float*)d_out, 4096, 2048, 2048);
}

// Round 3
// 491.318 us; speedup vs baseline: 1.4327x; 1.4327x over previous
//
#include <hip/hip_runtime.h>

// GQA forward on MI355X. bf16 MFMA everywhere, f32 accum.
// H=16 heads, G=4 groups, D=2048, HD=128, KV=512, bs=2, s=2048.
// NOTE: reference's _expand_kv is a RAW RESHAPE (scramble), not a transpose:
//   k[b,h,t',d] = Kp[b, h*128 + t'/16, (t'%4)*128 + d]   (same for v)
//
// R3 change (attn only): kill reg-staging spills (R2: VGPR=84, 322MB scratch
// writes). K/V now staged via global_load_lds direct (linear LDS dest +
// pre-swizzled per-lane global source, XOR involution; reads keep the same
// swizzle) + double-buffered LDS with counted s_waitcnt vmcnt(8) and raw
// s_barrier so next-tile loads stay in flight across the barrier.

#define DEV __device__ __forceinline__

typedef float f32x4 __attribute__((ext_vector_type(4)));
typedef __bf16 bf16x8 __attribute__((ext_vector_type(8)));

DEV f32x4 mfma16(bf16x8 a, bf16x8 b, f32x4 c) {
  return __builtin_amdgcn_mfma_f32_16x16x32_bf16(a, b, c, 0, 0, 0);
}

// async global->LDS, 16B per lane. LDS dest = wave-uniform base + lane*16;
// global source address is PER-LANE.
DEV void gld16(const void* gsrc, void* ldst) {
  __builtin_amdgcn_global_load_lds(
      (const __attribute__((address_space(1))) unsigned int*)gsrc,
      (__attribute__((address_space(3))) unsigned int*)ldst, 16, 0, 0);
}

// ---------------- X f32 -> bf16 ----------------
__global__ void convert_f32_bf16(const float* __restrict__ in, __bf16* __restrict__ out) {
  size_t i = ((size_t)blockIdx.x * 256 + threadIdx.x) * 8;
  float4 a = *(const float4*)(in + i);
  float4 b = *(const float4*)(in + i + 4);
  bf16x8 v;
  v[0] = (__bf16)a.x; v[1] = (__bf16)a.y; v[2] = (__bf16)a.z; v[3] = (__bf16)a.w;
  v[4] = (__bf16)b.x; v[5] = (__bf16)b.y; v[6] = (__bf16)b.z; v[7] = (__bf16)b.w;
  *(bf16x8*)(out + i) = v;
}

// ---------------- W [K][N] f32 -> WT [N][K] bf16 ----------------
__global__ void transpose_w_bf16(const float* __restrict__ W, __bf16* __restrict__ WT,
                                 int K, int N) {
  __shared__ float t[32][33];
  int tx = threadIdx.x & 31, ty = threadIdx.x >> 5;  // 32x8
  int n0 = blockIdx.x * 32, k0 = blockIdx.y * 32;
#pragma unroll
  for (int i = 0; i < 4; i++)
    t[ty + i * 8][tx] = W[(size_t)(k0 + ty + i * 8) * N + n0 + tx];
  __syncthreads();
#pragma unroll
  for (int i = 0; i < 4; i++)
    WT[(size_t)(n0 + ty + i * 8) * K + k0 + tx] = (__bf16)t[tx][ty + i * 8];
}

// ---------------- GEMM: C[M][N] = A[M][K] * Bt[N][K]^T + bias, m97 structure ----------------
template <int F32OUT>
__global__ __launch_bounds__(256, 2)
void gemm_bt(const __bf16* __restrict__ A, const __bf16* __restrict__ Bt,
             const float* __restrict__ bias, float scale, void* __restrict__ Cout,
             int M, int N, int K) {
  __shared__ __bf16 As[128 * 32];
  __shared__ __bf16 Bs[128 * 32];
  int tid = threadIdx.x, lane = tid & 63, w = tid >> 6;
  int wm = w >> 1, wn = w & 1, lg = lane >> 4, lc = lane & 15;
  int m0 = blockIdx.y * 128, n0 = blockIdx.x * 128;
  int srow = w * 16 + (lane >> 2), scol = (lane & 3) * 8;  // stage: 16B/lane
  const __bf16* Ag = A + (size_t)(m0 + srow) * K + scol;
  const __bf16* Bg = Bt + (size_t)(n0 + srow) * K + scol;
  f32x4 acc[4][4] = {};
  int nk = K >> 5;
  for (int kt = 0; kt < nk; ++kt) {
    if (kt) __syncthreads();
    const __bf16* a = Ag + kt * 32;
    const __bf16* bp = Bg + kt * 32;
    gld16((void*)a, As + (w * 16) * 32);
    gld16((void*)(a + (size_t)64 * K), As + (64 + w * 16) * 32);
    gld16((void*)bp, Bs + (w * 16) * 32);
    gld16((void*)(bp + (size_t)64 * K), Bs + (64 + w * 16) * 32);
    __syncthreads();
    bf16x8 af[4], bf[4];
#pragma unroll
    for (int i = 0; i < 4; i++)
      af[i] = *(const bf16x8*)(As + (wm * 64 + i * 16 + lc) * 32 + lg * 8);
#pragma unroll
    for (int i = 0; i < 4; i++)
      bf[i] = *(const bf16x8*)(Bs + (wn * 64 + i * 16 + lc) * 32 + lg * 8);
#pragma unroll
    for (int mi = 0; mi < 4; mi++)
#pragma unroll
      for (int ni = 0; ni < 4; ni++)
        acc[mi][ni] = mfma16(af[mi], bf[ni], acc[mi][ni]);
  }
  float bcol[4];
#pragma unroll
  for (int ni = 0; ni < 4; ni++) bcol[ni] = bias[n0 + wn * 64 + ni * 16 + lc];
#pragma unroll
  for (int mi = 0; mi < 4; mi++)
#pragma unroll
    for (int ni = 0; ni < 4; ni++)
#pragma unroll
      for (int r = 0; r < 4; r++) {
        int row = m0 + wm * 64 + mi * 16 + lg * 4 + r;
        int col = n0 + wn * 64 + ni * 16 + lc;
        float v = (acc[mi][ni][r] + bcol[ni]) * scale;
        if (F32OUT)
          ((float*)Cout)[(size_t)row * N + col] = v;
        else
          ((__bf16*)Cout)[(size_t)row * N + col] = (__bf16)v;
      }
}

// ---------------- expand/scramble KV ----------------
// Kx[bh][t'][d] = Kp[b*2048 + h*128 + t'/16][(t'%4)*128 + d]
// Vxt[bh][d][t'] = Vp[ same row ][(t'%4)*128 + d]   (transposed for PV B-frags)
__global__ void expand_kv(const __bf16* __restrict__ Kp, const __bf16* __restrict__ Vp,
                          __bf16* __restrict__ Kx, __bf16* __restrict__ Vxt) {
  __shared__ __bf16 Kl[16][512];
  __shared__ __bf16 Vl[16][512];
  int tid = threadIdx.x;
  int bh = blockIdx.x >> 3, tc = blockIdx.x & 7;
  int b = bh >> 4, h = bh & 15;
  size_t srow0 = (size_t)b * 2048 + h * 128 + tc * 16;
#pragma unroll
  for (int it = 0; it < 4; ++it) {
    int idx = it * 256 + tid;
    int rr = idx >> 6, ch = idx & 63;
    *(float4*)(&Kl[rr][ch * 8]) = *(const float4*)(Kp + (srow0 + rr) * 512 + ch * 8);
    *(float4*)(&Vl[rr][ch * 8]) = *(const float4*)(Vp + (srow0 + rr) * 512 + ch * 8);
  }
  __syncthreads();
#pragma unroll
  for (int it = 0; it < 16; ++it) {  // Kx: 256 t' x 128 d
    int idx = it * 256 + tid;
    int tloc = idx >> 4, ch = idx & 15;
    int tp = tc * 256 + tloc, rr = tloc >> 4, g = tloc & 3;
    *(float4*)(Kx + ((size_t)bh * 2048 + tp) * 128 + ch * 8) =
        *(const float4*)(&Kl[rr][g * 128 + ch * 8]);
  }
#pragma unroll
  for (int it = 0; it < 16; ++it) {  // Vxt: 128 d x 256 t'
    int idx = it * 256 + tid;
    int d = idx >> 5, c8 = idx & 31;
    int rr = c8 >> 1;
    bf16x8 v;
#pragma unroll
    for (int j = 0; j < 8; j++) v[j] = Vl[rr][(j & 3) * 128 + d];
    *(bf16x8*)(Vxt + ((size_t)bh * 128 + d) * 2048 + tc * 256 + c8 * 8) = v;
  }
}

// ---------------- flash attention, causal ----------------
// block = 4 waves, QBLK=64 (16 q-rows/wave), KVBLK=64, HD=128.
// Q pre-scaled by log2e/sqrt(128); softmax in exp2 domain.
// K/V staged by global_load_lds into double-buffered LDS; source pre-swizzled.
__global__ __launch_bounds__(256, 2)
void attn_fwd(const __bf16* __restrict__ Qb, const __bf16* __restrict__ Kx,
              const __bf16* __restrict__ Vxt, __bf16* __restrict__ attO) {
  __shared__ alignas(16) char Ks[2][16384];   // [t'=64][256B] linear, src-swizzled
  __shared__ alignas(16) char Vts[2][16384];  // [d=128][128B] linear, src-swizzled
  __shared__ alignas(16) char Ps[4 * 2048];   // per-wave P [16 q][64 t'] bf16
  int tid = threadIdx.x, lane = tid & 63, w = tid >> 6;
  int lg = lane >> 4, lc = lane & 15;
  int qt = 31 - (int)blockIdx.x;  // heavy blocks first
  int bh = blockIdx.y, b = bh >> 4, h = bh & 15;
  int q0 = qt * 64;
  const __bf16* Qrow = Qb + (size_t)(b * 2048 + q0 + w * 16 + lc) * 2048 + h * 128 + lg * 8;
  bf16x8 qf[4];
#pragma unroll
  for (int ks = 0; ks < 4; ks++) qf[ks] = *(const bf16x8*)(Qrow + ks * 32);
  f32x4 o[8] = {};
  float mrow[4], lrow[4];
#pragma unroll
  for (int r = 0; r < 4; r++) { mrow[r] = -3.0e38f; lrow[r] = 0.f; }
  const char* KgB = (const char*)(Kx + (size_t)bh * 2048 * 128);   // K row = 256B
  const char* VgB = (const char*)(Vxt + (size_t)bh * 128 * 2048);  // Vt row = 4096B
  char* Psw = Ps + w * 2048;

  // per-wave staging: 4 gld16 for K rows [w*16,w*16+16), 4 for Vt rows [w*32,w*32+32)
  // lane->global src carries the XOR swizzle; LDS dest is linear.
#define STAGE_KV(bufi, ktile)                                                            \
  do {                                                                                   \
    _Pragma("unroll") for (int seg = 0; seg < 4; seg++) {                                \
      int kr = w * 16 + seg * 4 + (lane >> 4);                                           \
      int off = ((lane & 15) * 16) ^ ((kr & 7) << 4);                                    \
      gld16(KgB + ((size_t)(ktile)*64 + kr) * 256 + off, &Ks[bufi][w * 4096 + seg * 1024]); \
    }                                                                                    \
    _Pragma("unroll") for (int seg = 0; seg < 4; seg++) {                                \
      int vr = w * 32 + seg * 8 + (lane >> 3);                                           \
      int off = ((lane & 7) * 16) ^ ((vr & 7) << 4);                                     \
      gld16(VgB + (size_t)vr * 4096 + (size_t)(ktile)*128 + off,                         \
            &Vts[bufi][w * 4096 + seg * 1024]);                                          \
    }                                                                                    \
  } while (0)

  STAGE_KV(0, 0);
  int cur = 0;
  for (int kt = 0; kt <= qt; ++kt) {
    if (kt < qt) {
      STAGE_KV(cur ^ 1, kt + 1);
      asm volatile("s_waitcnt vmcnt(8)" ::: "memory");  // this tile's 8 landed; next 8 in flight
    } else {
      asm volatile("s_waitcnt vmcnt(0)" ::: "memory");
    }
    __builtin_amdgcn_s_barrier();

    // QK^T: S[16q][64t']
    f32x4 s[4];
#pragma unroll
    for (int nt = 0; nt < 4; nt++) {
      s[nt] = (f32x4){0.f, 0.f, 0.f, 0.f};
#pragma unroll
      for (int ks = 0; ks < 4; ks++) {
        int trow = nt * 16 + lc;
        bf16x8 kf =
            *(const bf16x8*)(&Ks[cur][trow * 256 + ((ks * 64 + lg * 16) ^ ((trow & 7) << 4))]);
        s[nt] = mfma16(qf[ks], kf, s[nt]);
      }
    }
    if (kt == qt) {  // causal mask on diagonal tile
#pragma unroll
      for (int nt = 0; nt < 4; nt++)
#pragma unroll
        for (int r = 0; r < 4; r++)
          if (nt * 16 + lc > w * 16 + lg * 4 + r) s[nt][r] = -3.0e38f;
    }
    // online softmax (rows live on 16-lane groups; reduce via shfl_xor 1,2,4,8)
#pragma unroll
    for (int r = 0; r < 4; r++) {
      float v = fmaxf(fmaxf(s[0][r], s[1][r]), fmaxf(s[2][r], s[3][r]));
      v = fmaxf(v, __shfl_xor(v, 1));
      v = fmaxf(v, __shfl_xor(v, 2));
      v = fmaxf(v, __shfl_xor(v, 4));
      v = fmaxf(v, __shfl_xor(v, 8));
      float mn = fmaxf(mrow[r], v);
      float sc = exp2f(mrow[r] - mn);
      mrow[r] = mn;
      lrow[r] *= sc;
#pragma unroll
      for (int dt = 0; dt < 8; dt++) o[dt][r] *= sc;
      float rs = 0.f;
#pragma unroll
      for (int nt = 0; nt < 4; nt++) {
        float p = exp2f(s[nt][r] - mn);
        s[nt][r] = p;
        rs += p;
      }
      rs += __shfl_xor(rs, 1);
      rs += __shfl_xor(rs, 2);
      rs += __shfl_xor(rs, 4);
      rs += __shfl_xor(rs, 8);
      lrow[r] += rs;
    }
    // P (C-layout) -> per-wave LDS, bf16, swizzled; then consumed as A-frags
#pragma unroll
    for (int nt = 0; nt < 4; nt++)
#pragma unroll
      for (int r = 0; r < 4; r++) {
        int row = lg * 4 + r, col = nt * 16 + lc;
        *(__bf16*)(Psw + row * 128 + ((((col >> 3) << 4) ^ ((row & 7) << 4)) | ((col & 7) << 1))) =
            (__bf16)s[nt][r];
      }
    asm volatile("" ::: "memory");  // keep P-writes before PV reads (TBAA guard)
    // PV: o[16q][128d] += P[16q][64t'] * Vt
#pragma unroll
    for (int dt = 0; dt < 8; dt++) {
#pragma unroll
      for (int ks = 0; ks < 2; ks++) {
        bf16x8 af = *(const bf16x8*)(Psw + lc * 128 + ((ks * 64 + lg * 16) ^ ((lc & 7) << 4)));
        int vrow = dt * 16 + lc;
        bf16x8 vf =
            *(const bf16x8*)(&Vts[cur][vrow * 128 + ((ks * 64 + lg * 16) ^ ((vrow & 7) << 4))]);
        o[dt] = mfma16(af, vf, o[dt]);
      }
    }
    __builtin_amdgcn_s_barrier();  // all waves done reading buf[cur] before overwrite
    cur ^= 1;
  }
  // epilogue: divide by l, store bf16 to attO[b*2048+q][h*128+d]
#pragma unroll
  for (int r = 0; r < 4; r++) {
    float inv = 1.0f / lrow[r];
    int row = b * 2048 + q0 + w * 16 + lg * 4 + r;
#pragma unroll
    for (int dt = 0; dt < 8; dt++)
      attO[(size_t)row * 2048 + h * 128 + dt * 16 + lc] = (__bf16)(o[dt][r] * inv);
  }
#undef STAGE_KV
}

extern "C" void kernel_launch(void* const* d_in, const int* in_sizes, int n_in,
                              void* d_out, int out_size, void* d_ws, size_t ws_size,
                              hipStream_t stream) {
  const float* X = (const float*)d_in[0];
  const float* Wq = (const float*)d_in[1];
  const float* bq = (const float*)d_in[2];
  const float* Wk = (const float*)d_in[3];
  const float* bk = (const float*)d_in[4];
  const float* Wv = (const float*)d_in[5];
  const float* bv = (const float*)d_in[6];
  const float* Wo = (const float*)d_in[7];
  const float* bo = (const float*)d_in[8];
  char* ws = (char*)d_ws;
  const size_t MB = 1024 * 1024;
  __bf16* Xb  = (__bf16*)(ws + 0);        // 16 MB
  __bf16* WqT = (__bf16*)(ws + 16 * MB);  // 8 MB
  __bf16* WkT = (__bf16*)(ws + 24 * MB);  // 2 MB
  __bf16* WvT = (__bf16*)(ws + 27 * MB);  // 2 MB
  __bf16* WoT = (__bf16*)(ws + 30 * MB);  // 8 MB
  __bf16* Qbf = (__bf16*)(ws + 38 * MB);  // 16 MB
  __bf16* Kp  = (__bf16*)(ws + 54 * MB);  // 4 MB
  __bf16* Vp  = (__bf16*)(ws + 58 * MB);  // 4 MB
  __bf16* Kx  = (__bf16*)(ws + 62 * MB);  // 16 MB
  __bf16* Vxt = (__bf16*)(ws + 78 * MB);  // 16 MB
  __bf16* aO  = (__bf16*)(ws + 94 * MB);  // 16 MB -> 110 MB total

  convert_f32_bf16<<<4096, 256, 0, stream>>>(X, Xb);
  transpose_w_bf16<<<dim3(64, 64), 256, 0, stream>>>(Wq, WqT, 2048, 2048);
  transpose_w_bf16<<<dim3(16, 64), 256, 0, stream>>>(Wk, WkT, 2048, 512);
  transpose_w_bf16<<<dim3(16, 64), 256, 0, stream>>>(Wv, WvT, 2048, 512);
  transpose_w_bf16<<<dim3(64, 64), 256, 0, stream>>>(Wo, WoT, 2048, 2048);

  // fold 1/sqrt(HD) * log2(e) into Q so softmax uses exp2 directly
  float qscale = 1.4426950408889634f * 0.08838834764831845f;
  gemm_bt<0><<<dim3(16, 32), 256, 0, stream>>>(Xb, WqT, bq, qscale, Qbf, 4096, 2048, 2048);
  gemm_bt<0><<<dim3(4, 32), 256, 0, stream>>>(Xb, WkT, bk, 1.0f, Kp, 4096, 512, 2048);
  gemm_bt<0><<<dim3(4, 32), 256, 0, stream>>>(Xb, WvT, bv, 1.0f, Vp, 4096, 512, 2048);

  expand_kv<<<256, 256, 0, stream>>>(Kp, Vp, Kx, Vxt);
  attn_fwd<<<dim3(32, 32), 256, 0, stream>>>(Qbf, Kx, Vxt, aO);

  gemm_bt<1><<<dim3(16, 32), 256, 0, stream>>>(aO, WoT, bo, 1.0f, (float*)d_out, 4096, 2048, 2048);
}

// Round 4
// 445.293 us; speedup vs baseline: 1.5808x; 1.1034x over previous
//
#include <hip/hip_runtime.h>

// GQA forward on MI355X. bf16 MFMA everywhere, f32 accum.
// H=16 heads, G=4 groups, D=2048, HD=128, KV=512, bs=2, s=2048.
// NOTE: reference's _expand_kv is a RAW RESHAPE (scramble), not a transpose:
//   k[b,h,t',d] = Kp[b, h*128 + t'/16, (t'%4)*128 + d]   (same for v)
//
// R4 change (attn only): R3 was latency-bound (occ 11%, 6.6K cyc/tile vs ~2K
// work). Single-buffer K/V -> 40KB LDS -> 4 blocks/CU (16 waves) for TLP;
// defer-max rescale skip (THR=8, exp2 domain); lane-partial row-sum reduced
// once in epilogue; s_setprio(1) around MFMA clusters.

#define DEV __device__ __forceinline__

typedef float f32x4 __attribute__((ext_vector_type(4)));
typedef __bf16 bf16x8 __attribute__((ext_vector_type(8)));

DEV f32x4 mfma16(bf16x8 a, bf16x8 b, f32x4 c) {
  return __builtin_amdgcn_mfma_f32_16x16x32_bf16(a, b, c, 0, 0, 0);
}

// async global->LDS, 16B per lane. LDS dest = wave-uniform base + lane*16;
// global source address is PER-LANE.
DEV void gld16(const void* gsrc, void* ldst) {
  __builtin_amdgcn_global_load_lds(
      (const __attribute__((address_space(1))) unsigned int*)gsrc,
      (__attribute__((address_space(3))) unsigned int*)ldst, 16, 0, 0);
}

// ---------------- X f32 -> bf16 ----------------
__global__ void convert_f32_bf16(const float* __restrict__ in, __bf16* __restrict__ out) {
  size_t i = ((size_t)blockIdx.x * 256 + threadIdx.x) * 8;
  float4 a = *(const float4*)(in + i);
  float4 b = *(const float4*)(in + i + 4);
  bf16x8 v;
  v[0] = (__bf16)a.x; v[1] = (__bf16)a.y; v[2] = (__bf16)a.z; v[3] = (__bf16)a.w;
  v[4] = (__bf16)b.x; v[5] = (__bf16)b.y; v[6] = (__bf16)b.z; v[7] = (__bf16)b.w;
  *(bf16x8*)(out + i) = v;
}

// ---------------- W [K][N] f32 -> WT [N][K] bf16 ----------------
__global__ void transpose_w_bf16(const float* __restrict__ W, __bf16* __restrict__ WT,
                                 int K, int N) {
  __shared__ float t[32][33];
  int tx = threadIdx.x & 31, ty = threadIdx.x >> 5;  // 32x8
  int n0 = blockIdx.x * 32, k0 = blockIdx.y * 32;
#pragma unroll
  for (int i = 0; i < 4; i++)
    t[ty + i * 8][tx] = W[(size_t)(k0 + ty + i * 8) * N + n0 + tx];
  __syncthreads();
#pragma unroll
  for (int i = 0; i < 4; i++)
    WT[(size_t)(n0 + ty + i * 8) * K + k0 + tx] = (__bf16)t[tx][ty + i * 8];
}

// ---------------- GEMM: C[M][N] = A[M][K] * Bt[N][K]^T + bias, m97 structure ----------------
template <int F32OUT>
__global__ __launch_bounds__(256, 2)
void gemm_bt(const __bf16* __restrict__ A, const __bf16* __restrict__ Bt,
             const float* __restrict__ bias, float scale, void* __restrict__ Cout,
             int M, int N, int K) {
  __shared__ __bf16 As[128 * 32];
  __shared__ __bf16 Bs[128 * 32];
  int tid = threadIdx.x, lane = tid & 63, w = tid >> 6;
  int wm = w >> 1, wn = w & 1, lg = lane >> 4, lc = lane & 15;
  int m0 = blockIdx.y * 128, n0 = blockIdx.x * 128;
  int srow = w * 16 + (lane >> 2), scol = (lane & 3) * 8;  // stage: 16B/lane
  const __bf16* Ag = A + (size_t)(m0 + srow) * K + scol;
  const __bf16* Bg = Bt + (size_t)(n0 + srow) * K + scol;
  f32x4 acc[4][4] = {};
  int nk = K >> 5;
  for (int kt = 0; kt < nk; ++kt) {
    if (kt) __syncthreads();
    const __bf16* a = Ag + kt * 32;
    const __bf16* bp = Bg + kt * 32;
    gld16((void*)a, As + (w * 16) * 32);
    gld16((void*)(a + (size_t)64 * K), As + (64 + w * 16) * 32);
    gld16((void*)bp, Bs + (w * 16) * 32);
    gld16((void*)(bp + (size_t)64 * K), Bs + (64 + w * 16) * 32);
    __syncthreads();
    bf16x8 af[4], bf[4];
#pragma unroll
    for (int i = 0; i < 4; i++)
      af[i] = *(const bf16x8*)(As + (wm * 64 + i * 16 + lc) * 32 + lg * 8);
#pragma unroll
    for (int i = 0; i < 4; i++)
      bf[i] = *(const bf16x8*)(Bs + (wn * 64 + i * 16 + lc) * 32 + lg * 8);
#pragma unroll
    for (int mi = 0; mi < 4; mi++)
#pragma unroll
      for (int ni = 0; ni < 4; ni++)
        acc[mi][ni] = mfma16(af[mi], bf[ni], acc[mi][ni]);
  }
  float bcol[4];
#pragma unroll
  for (int ni = 0; ni < 4; ni++) bcol[ni] = bias[n0 + wn * 64 + ni * 16 + lc];
#pragma unroll
  for (int mi = 0; mi < 4; mi++)
#pragma unroll
    for (int ni = 0; ni < 4; ni++)
#pragma unroll
      for (int r = 0; r < 4; r++) {
        int row = m0 + wm * 64 + mi * 16 + lg * 4 + r;
        int col = n0 + wn * 64 + ni * 16 + lc;
        float v = (acc[mi][ni][r] + bcol[ni]) * scale;
        if (F32OUT)
          ((float*)Cout)[(size_t)row * N + col] = v;
        else
          ((__bf16*)Cout)[(size_t)row * N + col] = (__bf16)v;
      }
}

// ---------------- expand/scramble KV ----------------
// Kx[bh][t'][d] = Kp[b*2048 + h*128 + t'/16][(t'%4)*128 + d]
// Vxt[bh][d][t'] = Vp[ same row ][(t'%4)*128 + d]   (transposed for PV B-frags)
__global__ void expand_kv(const __bf16* __restrict__ Kp, const __bf16* __restrict__ Vp,
                          __bf16* __restrict__ Kx, __bf16* __restrict__ Vxt) {
  __shared__ __bf16 Kl[16][512];
  __shared__ __bf16 Vl[16][512];
  int tid = threadIdx.x;
  int bh = blockIdx.x >> 3, tc = blockIdx.x & 7;
  int b = bh >> 4, h = bh & 15;
  size_t srow0 = (size_t)b * 2048 + h * 128 + tc * 16;
#pragma unroll
  for (int it = 0; it < 4; ++it) {
    int idx = it * 256 + tid;
    int rr = idx >> 6, ch = idx & 63;
    *(float4*)(&Kl[rr][ch * 8]) = *(const float4*)(Kp + (srow0 + rr) * 512 + ch * 8);
    *(float4*)(&Vl[rr][ch * 8]) = *(const float4*)(Vp + (srow0 + rr) * 512 + ch * 8);
  }
  __syncthreads();
#pragma unroll
  for (int it = 0; it < 16; ++it) {  // Kx: 256 t' x 128 d
    int idx = it * 256 + tid;
    int tloc = idx >> 4, ch = idx & 15;
    int tp = tc * 256 + tloc, rr = tloc >> 4, g = tloc & 3;
    *(float4*)(Kx + ((size_t)bh * 2048 + tp) * 128 + ch * 8) =
        *(const float4*)(&Kl[rr][g * 128 + ch * 8]);
  }
#pragma unroll
  for (int it = 0; it < 16; ++it) {  // Vxt: 128 d x 256 t'
    int idx = it * 256 + tid;
    int d = idx >> 5, c8 = idx & 31;
    int rr = c8 >> 1;
    bf16x8 v;
#pragma unroll
    for (int j = 0; j < 8; j++) v[j] = Vl[rr][(j & 3) * 128 + d];
    *(bf16x8*)(Vxt + ((size_t)bh * 128 + d) * 2048 + tc * 256 + c8 * 8) = v;
  }
}

// ---------------- flash attention, causal ----------------
// block = 4 waves, QBLK=64 (16 q-rows/wave), KVBLK=64, HD=128, 40KB LDS.
// Q pre-scaled by log2e/sqrt(128); softmax in exp2 domain.
// Single-buffered K/V staged by global_load_lds (pre-swizzled source);
// latency covered by 4 blocks/CU TLP. Defer-max rescale skip, THR=8.
__global__ __launch_bounds__(256, 4)
void attn_fwd(const __bf16* __restrict__ Qb, const __bf16* __restrict__ Kx,
              const __bf16* __restrict__ Vxt, __bf16* __restrict__ attO) {
  __shared__ alignas(16) char Ks[16384];   // [t'=64][256B] linear, src-swizzled
  __shared__ alignas(16) char Vts[16384];  // [d=128][128B] linear, src-swizzled
  __shared__ alignas(16) char Ps[4 * 2048];  // per-wave P [16 q][64 t'] bf16
  int tid = threadIdx.x, lane = tid & 63, w = tid >> 6;
  int lg = lane >> 4, lc = lane & 15;
  int qt = 31 - (int)blockIdx.x;  // heavy blocks first
  int bh = blockIdx.y, b = bh >> 4, h = bh & 15;
  int q0 = qt * 64;
  const __bf16* Qrow = Qb + (size_t)(b * 2048 + q0 + w * 16 + lc) * 2048 + h * 128 + lg * 8;
  bf16x8 qf[4];
#pragma unroll
  for (int ks = 0; ks < 4; ks++) qf[ks] = *(const bf16x8*)(Qrow + ks * 32);
  f32x4 o[8] = {};
  float mrow[4], lsum[4];
#pragma unroll
  for (int r = 0; r < 4; r++) { mrow[r] = -3.0e38f; lsum[r] = 0.f; }
  const char* KgB = (const char*)(Kx + (size_t)bh * 2048 * 128);   // K row = 256B
  const char* VgB = (const char*)(Vxt + (size_t)bh * 128 * 2048);  // Vt row = 4096B
  char* Psw = Ps + w * 2048;

  // per-wave staging: 4 gld16 for K rows [w*16,w*16+16), 4 for Vt rows [w*32,w*32+32)
  // lane->global src carries the XOR swizzle; LDS dest is linear.
#define STAGE_KV(ktile)                                                                  \
  do {                                                                                   \
    _Pragma("unroll") for (int seg = 0; seg < 4; seg++) {                                \
      int kr = w * 16 + seg * 4 + (lane >> 4);                                           \
      int off = ((lane & 15) * 16) ^ ((kr & 7) << 4);                                    \
      gld16(KgB + ((size_t)(ktile)*64 + kr) * 256 + off, &Ks[w * 4096 + seg * 1024]);    \
    }                                                                                    \
    _Pragma("unroll") for (int seg = 0; seg < 4; seg++) {                                \
      int vr = w * 32 + seg * 8 + (lane >> 3);                                           \
      int off = ((lane & 7) * 16) ^ ((vr & 7) << 4);                                     \
      gld16(VgB + (size_t)vr * 4096 + (size_t)(ktile)*128 + off,                         \
            &Vts[w * 4096 + seg * 1024]);                                                \
    }                                                                                    \
  } while (0)

  for (int kt = 0; kt <= qt; ++kt) {
    if (kt) __builtin_amdgcn_s_barrier();  // all waves done reading before overwrite
    STAGE_KV(kt);
    asm volatile("s_waitcnt vmcnt(0)" ::: "memory");
    __builtin_amdgcn_s_barrier();

    // QK^T: S[16q][64t']
    f32x4 s[4];
    __builtin_amdgcn_s_setprio(1);
#pragma unroll
    for (int nt = 0; nt < 4; nt++) {
      s[nt] = (f32x4){0.f, 0.f, 0.f, 0.f};
#pragma unroll
      for (int ks = 0; ks < 4; ks++) {
        int trow = nt * 16 + lc;
        bf16x8 kf =
            *(const bf16x8*)(&Ks[trow * 256 + ((ks * 64 + lg * 16) ^ ((trow & 7) << 4))]);
        s[nt] = mfma16(qf[ks], kf, s[nt]);
      }
    }
    __builtin_amdgcn_s_setprio(0);
    if (kt == qt) {  // causal mask on diagonal tile
#pragma unroll
      for (int nt = 0; nt < 4; nt++)
#pragma unroll
        for (int r = 0; r < 4; r++)
          if (nt * 16 + lc > w * 16 + lg * 4 + r) s[nt][r] = -3.0e38f;
    }
    // online softmax, exp2 domain. Row r lives on the 16-lane group; per-tile
    // row-max reduce always; rescale of o/lsum SKIPPED unless max grew > 8.
    float vmax[4];
#pragma unroll
    for (int r = 0; r < 4; r++) {
      float v = fmaxf(fmaxf(s[0][r], s[1][r]), fmaxf(s[2][r], s[3][r]));
      v = fmaxf(v, __shfl_xor(v, 1));
      v = fmaxf(v, __shfl_xor(v, 2));
      v = fmaxf(v, __shfl_xor(v, 4));
      v = fmaxf(v, __shfl_xor(v, 8));
      vmax[r] = v;
    }
    bool need = false;
#pragma unroll
    for (int r = 0; r < 4; r++) need |= (vmax[r] > mrow[r] + 8.0f);
    if (__any((int)need)) {  // rescale path (rare in steady state)
#pragma unroll
      for (int r = 0; r < 4; r++) {
        float mn = fmaxf(mrow[r], vmax[r]);
        float sc = exp2f(mrow[r] - mn);
        mrow[r] = mn;
        lsum[r] *= sc;
#pragma unroll
        for (int dt = 0; dt < 8; dt++) o[dt][r] *= sc;
      }
    }
#pragma unroll
    for (int r = 0; r < 4; r++) {
      float rs = 0.f;
#pragma unroll
      for (int nt = 0; nt < 4; nt++) {
        float p = exp2f(s[nt][r] - mrow[r]);  // bounded by 2^8
        s[nt][r] = p;
        rs += p;
      }
      lsum[r] += rs;  // lane-partial; reduced once in epilogue
    }
    // P (C-layout) -> per-wave LDS, bf16, swizzled; then consumed as A-frags
#pragma unroll
    for (int nt = 0; nt < 4; nt++)
#pragma unroll
      for (int r = 0; r < 4; r++) {
        int row = lg * 4 + r, col = nt * 16 + lc;
        *(__bf16*)(Psw + row * 128 + ((((col >> 3) << 4) ^ ((row & 7) << 4)) | ((col & 7) << 1))) =
            (__bf16)s[nt][r];
      }
    asm volatile("" ::: "memory");  // keep P-writes before PV reads (TBAA guard)
    // PV: o[16q][128d] += P[16q][64t'] * Vt
    __builtin_amdgcn_s_setprio(1);
#pragma unroll
    for (int dt = 0; dt < 8; dt++) {
#pragma unroll
      for (int ks = 0; ks < 2; ks++) {
        bf16x8 af = *(const bf16x8*)(Psw + lc * 128 + ((ks * 64 + lg * 16) ^ ((lc & 7) << 4)));
        int vrow = dt * 16 + lc;
        bf16x8 vf =
            *(const bf16x8*)(&Vts[vrow * 128 + ((ks * 64 + lg * 16) ^ ((vrow & 7) << 4))]);
        o[dt] = mfma16(af, vf, o[dt]);
      }
    }
    __builtin_amdgcn_s_setprio(0);
  }
  // epilogue: reduce lane-partial row sums, divide, store bf16
#pragma unroll
  for (int r = 0; r < 4; r++) {
    float rs = lsum[r];
    rs += __shfl_xor(rs, 1);
    rs += __shfl_xor(rs, 2);
    rs += __shfl_xor(rs, 4);
    rs += __shfl_xor(rs, 8);
    float inv = 1.0f / rs;
    int row = b * 2048 + q0 + w * 16 + lg * 4 + r;
#pragma unroll
    for (int dt = 0; dt < 8; dt++)
      attO[(size_t)row * 2048 + h * 128 + dt * 16 + lc] = (__bf16)(o[dt][r] * inv);
  }
#undef STAGE_KV
}

extern "C" void kernel_launch(void* const* d_in, const int* in_sizes, int n_in,
                              void* d_out, int out_size, void* d_ws, size_t ws_size,
                              hipStream_t stream) {
  const float* X = (const float*)d_in[0];
  const float* Wq = (const float*)d_in[1];
  const float* bq = (const float*)d_in[2];
  const float* Wk = (const float*)d_in[3];
  const float* bk = (const float*)d_in[4];
  const float* Wv = (const float*)d_in[5];
  const float* bv = (const float*)d_in[6];
  const float* Wo = (const float*)d_in[7];
  const float* bo = (const float*)d_in[8];
  char* ws = (char*)d_ws;
  const size_t MB = 1024 * 1024;
  __bf16* Xb  = (__bf16*)(ws + 0);        // 16 MB
  __bf16* WqT = (__bf16*)(ws + 16 * MB);  // 8 MB
  __bf16* WkT = (__bf16*)(ws + 24 * MB);  // 2 MB
  __bf16* WvT = (__bf16*)(ws + 27 * MB);  // 2 MB
  __bf16* WoT = (__bf16*)(ws + 30 * MB);  // 8 MB
  __bf16* Qbf = (__bf16*)(ws + 38 * MB);  // 16 MB
  __bf16* Kp  = (__bf16*)(ws + 54 * MB);  // 4 MB
  __bf16* Vp  = (__bf16*)(ws + 58 * MB);  // 4 MB
  __bf16* Kx  = (__bf16*)(ws + 62 * MB);  // 16 MB
  __bf16* Vxt = (__bf16*)(ws + 78 * MB);  // 16 MB
  __bf16* aO  = (__bf16*)(ws + 94 * MB);  // 16 MB -> 110 MB total

  convert_f32_bf16<<<4096, 256, 0, stream>>>(X, Xb);
  transpose_w_bf16<<<dim3(64, 64), 256, 0, stream>>>(Wq, WqT, 2048, 2048);
  transpose_w_bf16<<<dim3(16, 64), 256, 0, stream>>>(Wk, WkT, 2048, 512);
  transpose_w_bf16<<<dim3(16, 64), 256, 0, stream>>>(Wv, WvT, 2048, 512);
  transpose_w_bf16<<<dim3(64, 64), 256, 0, stream>>>(Wo, WoT, 2048, 2048);

  // fold 1/sqrt(HD) * log2(e) into Q so softmax uses exp2 directly
  float qscale = 1.4426950408889634f * 0.08838834764831845f;
  gemm_bt<0><<<dim3(16, 32), 256, 0, stream>>>(Xb, WqT, bq, qscale, Qbf, 4096, 2048, 2048);
  gemm_bt<0><<<dim3(4, 32), 256, 0, stream>>>(Xb, WkT, bk, 1.0f, Kp, 4096, 512, 2048);
  gemm_bt<0><<<dim3(4, 32), 256, 0, stream>>>(Xb, WvT, bv, 1.0f, Vp, 4096, 512, 2048);

  expand_kv<<<256, 256, 0, stream>>>(Kp, Vp, Kx, Vxt);
  attn_fwd<<<dim3(32, 32), 256, 0, stream>>>(Qbf, Kx, Vxt, aO);

  gemm_bt<1><<<dim3(16, 32), 256, 0, stream>>>(aO, WoT, bo, 1.0f, (float*)d_out, 4096, 2048, 2048);
}

// Round 5
// 403.301 us; speedup vs baseline: 1.7454x; 1.1041x over previous
//
#include <hip/hip_runtime.h>

// GQA forward on MI355X. bf16 MFMA everywhere, f32 accum.
// H=16 heads, G=4 groups, D=2048, HD=128, KV=512, bs=2, s=2048.
// Reference's _expand_kv is a RAW RESHAPE:
//   k[b,h,t',d] = Kp[b, h*128 + t'/16, (t'%4)*128 + d]   (same for v)
// => a 64-t' K tile = ONE 1KB Kp row (4KB unique, 4x duplicated in t').
//
// R5 changes (attn only):
//  - K staged directly from Kp, 4KB/tile (1 gld16/wave), Kx buffer deleted.
//    Seg-XOR swizzle (byte ^= seg*32) keeps fragment reads ~2-way.
//  - Swapped QK^T: sT = mfma(K,Q) -> P lane-local per q-row: row stats scalar,
//    2 shfls (was 32), P stored as 4x ds_write_b64 (was 16x b16).
//  - LDS 28KB -> 5 blocks/CU.

#define DEV __device__ __forceinline__

typedef float f32x4 __attribute__((ext_vector_type(4)));
typedef __bf16 bf16x8 __attribute__((ext_vector_type(8)));
typedef __bf16 bf16x4 __attribute__((ext_vector_type(4)));

DEV f32x4 mfma16(bf16x8 a, bf16x8 b, f32x4 c) {
  return __builtin_amdgcn_mfma_f32_16x16x32_bf16(a, b, c, 0, 0, 0);
}

// async global->LDS, 16B/lane. LDS dest = wave-uniform base + lane*16;
// global source address is PER-LANE.
DEV void gld16(const void* gsrc, void* ldst) {
  __builtin_amdgcn_global_load_lds(
      (const __attribute__((address_space(1))) unsigned int*)gsrc,
      (__attribute__((address_space(3))) unsigned int*)ldst, 16, 0, 0);
}

// ---------------- X f32 -> bf16 ----------------
__global__ void convert_f32_bf16(const float* __restrict__ in, __bf16* __restrict__ out) {
  size_t i = ((size_t)blockIdx.x * 256 + threadIdx.x) * 8;
  float4 a = *(const float4*)(in + i);
  float4 b = *(const float4*)(in + i + 4);
  bf16x8 v;
  v[0] = (__bf16)a.x; v[1] = (__bf16)a.y; v[2] = (__bf16)a.z; v[3] = (__bf16)a.w;
  v[4] = (__bf16)b.x; v[5] = (__bf16)b.y; v[6] = (__bf16)b.z; v[7] = (__bf16)b.w;
  *(bf16x8*)(out + i) = v;
}

// ---------------- W [K][N] f32 -> WT [N][K] bf16 ----------------
__global__ void transpose_w_bf16(const float* __restrict__ W, __bf16* __restrict__ WT,
                                 int K, int N) {
  __shared__ float t[32][33];
  int tx = threadIdx.x & 31, ty = threadIdx.x >> 5;  // 32x8
  int n0 = blockIdx.x * 32, k0 = blockIdx.y * 32;
#pragma unroll
  for (int i = 0; i < 4; i++)
    t[ty + i * 8][tx] = W[(size_t)(k0 + ty + i * 8) * N + n0 + tx];
  __syncthreads();
#pragma unroll
  for (int i = 0; i < 4; i++)
    WT[(size_t)(n0 + ty + i * 8) * K + k0 + tx] = (__bf16)t[tx][ty + i * 8];
}

// ---------------- GEMM: C[M][N] = A[M][K] * Bt[N][K]^T + bias, m97 structure ----------------
template <int F32OUT>
__global__ __launch_bounds__(256, 2)
void gemm_bt(const __bf16* __restrict__ A, const __bf16* __restrict__ Bt,
             const float* __restrict__ bias, float scale, void* __restrict__ Cout,
             int M, int N, int K) {
  __shared__ __bf16 As[128 * 32];
  __shared__ __bf16 Bs[128 * 32];
  int tid = threadIdx.x, lane = tid & 63, w = tid >> 6;
  int wm = w >> 1, wn = w & 1, lg = lane >> 4, lc = lane & 15;
  int m0 = blockIdx.y * 128, n0 = blockIdx.x * 128;
  int srow = w * 16 + (lane >> 2), scol = (lane & 3) * 8;  // stage: 16B/lane
  const __bf16* Ag = A + (size_t)(m0 + srow) * K + scol;
  const __bf16* Bg = Bt + (size_t)(n0 + srow) * K + scol;
  f32x4 acc[4][4] = {};
  int nk = K >> 5;
  for (int kt = 0; kt < nk; ++kt) {
    if (kt) __syncthreads();
    const __bf16* a = Ag + kt * 32;
    const __bf16* bp = Bg + kt * 32;
    gld16((void*)a, As + (w * 16) * 32);
    gld16((void*)(a + (size_t)64 * K), As + (64 + w * 16) * 32);
    gld16((void*)bp, Bs + (w * 16) * 32);
    gld16((void*)(bp + (size_t)64 * K), Bs + (64 + w * 16) * 32);
    __syncthreads();
    bf16x8 af[4], bf[4];
#pragma unroll
    for (int i = 0; i < 4; i++)
      af[i] = *(const bf16x8*)(As + (wm * 64 + i * 16 + lc) * 32 + lg * 8);
#pragma unroll
    for (int i = 0; i < 4; i++)
      bf[i] = *(const bf16x8*)(Bs + (wn * 64 + i * 16 + lc) * 32 + lg * 8);
#pragma unroll
    for (int mi = 0; mi < 4; mi++)
#pragma unroll
      for (int ni = 0; ni < 4; ni++)
        acc[mi][ni] = mfma16(af[mi], bf[ni], acc[mi][ni]);
  }
  float bcol[4];
#pragma unroll
  for (int ni = 0; ni < 4; ni++) bcol[ni] = bias[n0 + wn * 64 + ni * 16 + lc];
#pragma unroll
  for (int mi = 0; mi < 4; mi++)
#pragma unroll
    for (int ni = 0; ni < 4; ni++)
#pragma unroll
      for (int r = 0; r < 4; r++) {
        int row = m0 + wm * 64 + mi * 16 + lg * 4 + r;
        int col = n0 + wn * 64 + ni * 16 + lc;
        float v = (acc[mi][ni][r] + bcol[ni]) * scale;
        if (F32OUT)
          ((float*)Cout)[(size_t)row * N + col] = v;
        else
          ((__bf16*)Cout)[(size_t)row * N + col] = (__bf16)v;
      }
}

// ---------------- expand V only ----------------
// Vxt[bh][d][t'] = Vp[b*2048 + h*128 + t'/16][(t'%4)*128 + d]
__global__ void expand_v(const __bf16* __restrict__ Vp, __bf16* __restrict__ Vxt) {
  __shared__ __bf16 Vl[16][512];
  int tid = threadIdx.x;
  int bh = blockIdx.x >> 3, tc = blockIdx.x & 7;
  int b = bh >> 4, h = bh & 15;
  size_t srow0 = (size_t)b * 2048 + h * 128 + tc * 16;
#pragma unroll
  for (int it = 0; it < 4; ++it) {
    int idx = it * 256 + tid;
    int rr = idx >> 6, ch = idx & 63;
    *(float4*)(&Vl[rr][ch * 8]) = *(const float4*)(Vp + (srow0 + rr) * 512 + ch * 8);
  }
  __syncthreads();
#pragma unroll
  for (int it = 0; it < 16; ++it) {  // Vxt: 128 d x 256 t'
    int idx = it * 256 + tid;
    int d = idx >> 5, c8 = idx & 31;
    int rr = c8 >> 1;
    bf16x8 v;
#pragma unroll
    for (int j = 0; j < 8; j++) v[j] = Vl[rr][(j & 3) * 128 + d];
    *(bf16x8*)(Vxt + ((size_t)bh * 128 + d) * 2048 + tc * 256 + c8 * 8) = v;
  }
}

// ---------------- flash attention, causal ----------------
// block = 4 waves, QBLK=64 (16 q-rows/wave), KVBLK=64, HD=128, 28KB LDS.
// Q pre-scaled by log2e/sqrt(128); softmax in exp2 domain, swapped QK^T
// (sT = K*Q^T) so each lane owns row stats for q=lc. Defer-max THR=8.
__global__ __launch_bounds__(256, 4)
void attn_fwd(const __bf16* __restrict__ Qb, const __bf16* __restrict__ Kp,
              const __bf16* __restrict__ Vxt, __bf16* __restrict__ attO) {
  __shared__ alignas(16) char Kl[4096];    // [nt=4][1KB Kp row], seg-XOR swizzled
  __shared__ alignas(16) char Vts[16384];  // [d=128][128B] linear, src-swizzled
  __shared__ alignas(16) char Ps[4 * 2048];  // per-wave P [16 q][64 t'] bf16
  int tid = threadIdx.x, lane = tid & 63, w = tid >> 6;
  int lg = lane >> 4, lc = lane & 15;
  int qt = 31 - (int)blockIdx.x;  // heavy blocks first
  int bh = blockIdx.y, b = bh >> 4, h = bh & 15;
  int q0 = qt * 64;
  const __bf16* Qrow = Qb + (size_t)(b * 2048 + q0 + w * 16 + lc) * 2048 + h * 128 + lg * 8;
  bf16x8 qf[4];
#pragma unroll
  for (int ks = 0; ks < 4; ks++) qf[ks] = *(const bf16x8*)(Qrow + ks * 32);
  f32x4 o[8] = {};
  float mrow = -3.0e38f, lsum = 0.f;  // stats for q = lc (replicated over lg)
  const char* KpB = (const char*)Kp + (size_t)(b * 2048 + h * 128) * 1024;  // 1KB rows
  const char* VgB = (const char*)(Vxt + (size_t)bh * 128 * 2048);           // 4KB rows
  char* Psw = Ps + w * 2048;

  // K: one 1KB Kp row per wave (row kt*4+w), seg-XOR pre-swizzle (byte^=seg*32)
  // V: 4 gld16/wave from Vxt rows [w*32, w*32+32), row-XOR pre-swizzle.
#define STAGE_KV(ktile)                                                                  \
  do {                                                                                   \
    {                                                                                    \
      int seg = lane >> 4, cb = (lane & 15) * 16;                                        \
      gld16(KpB + (size_t)((ktile)*4 + w) * 1024 + seg * 256 + (cb ^ (seg * 32)),        \
            &Kl[w * 1024]);                                                              \
    }                                                                                    \
    _Pragma("unroll") for (int seg = 0; seg < 4; seg++) {                                \
      int vr = w * 32 + seg * 8 + (lane >> 3);                                           \
      int off = ((lane & 7) * 16) ^ ((vr & 7) << 4);                                     \
      gld16(VgB + (size_t)vr * 4096 + (size_t)(ktile)*128 + off,                         \
            &Vts[w * 4096 + seg * 1024]);                                                \
    }                                                                                    \
  } while (0)

  for (int kt = 0; kt <= qt; ++kt) {
    if (kt) __builtin_amdgcn_s_barrier();  // all waves done reading before overwrite
    STAGE_KV(kt);
    asm volatile("s_waitcnt vmcnt(0)" ::: "memory");
    __builtin_amdgcn_s_barrier();

    // swapped QK^T: sT[nt][r] = S[t' = nt*16+lg*4+r][q = lc]
    f32x4 s[4];
    __builtin_amdgcn_s_setprio(1);
#pragma unroll
    for (int nt = 0; nt < 4; nt++) {
      s[nt] = (f32x4){0.f, 0.f, 0.f, 0.f};
#pragma unroll
      for (int ks = 0; ks < 4; ks++) {
        int seg = lc & 3;
        bf16x8 kf =
            *(const bf16x8*)(&Kl[nt * 1024 + seg * 256 + ((ks * 64 + lg * 16) ^ (seg * 32))]);
        s[nt] = mfma16(kf, qf[ks], s[nt]);
      }
    }
    __builtin_amdgcn_s_setprio(0);
    if (kt == qt) {  // causal: mask t'_loc > q_loc (q_loc = w*16+lc)
#pragma unroll
      for (int nt = 0; nt < 4; nt++)
#pragma unroll
        for (int r = 0; r < 4; r++)
          if (nt * 16 + lg * 4 + r > w * 16 + lc) s[nt][r] = -3.0e38f;
    }
    // row stats: lane-local max over 16 vals, then reduce across lg (xor 16,32)
    float v = -3.0e38f;
#pragma unroll
    for (int nt = 0; nt < 4; nt++)
#pragma unroll
      for (int r = 0; r < 4; r++) v = fmaxf(v, s[nt][r]);
    v = fmaxf(v, __shfl_xor(v, 16));
    v = fmaxf(v, __shfl_xor(v, 32));
    if (__any(v > mrow + 8.0f)) {  // rescale path (rare after first tile)
      float mn = fmaxf(mrow, v);
      float sc = exp2f(mrow - mn);
      mrow = mn;
      lsum *= sc;
#pragma unroll
      for (int r = 0; r < 4; r++) {
        float scr = __shfl(sc, lg * 4 + r);  // scale of o-row q=lg*4+r
#pragma unroll
        for (int dt = 0; dt < 8; dt++) o[dt][r] *= scr;
      }
    }
    float rs = 0.f;
#pragma unroll
    for (int nt = 0; nt < 4; nt++)
#pragma unroll
      for (int r = 0; r < 4; r++) {
        float p = exp2f(s[nt][r] - mrow);  // bounded by 2^8
        s[nt][r] = p;
        rs += p;
      }
    lsum += rs;  // lane-local; reduced in epilogue
    // P -> per-wave LDS: row q=lc, 4 consecutive t' per (nt) as one b64 write
#pragma unroll
    for (int nt = 0; nt < 4; nt++) {
      bf16x4 pk;
#pragma unroll
      for (int r = 0; r < 4; r++) pk[r] = (__bf16)s[nt][r];
      *(bf16x4*)(Psw + lc * 128 + ((nt * 32 + lg * 8) ^ ((lc & 7) << 4))) = pk;
    }
    asm volatile("" ::: "memory");  // keep P-writes before PV reads (TBAA guard)
    // PV: o[16q][128d] += P[16q][64t'] * Vt
    __builtin_amdgcn_s_setprio(1);
    bf16x8 af[2];
#pragma unroll
    for (int ks = 0; ks < 2; ks++)
      af[ks] = *(const bf16x8*)(Psw + lc * 128 + ((ks * 64 + lg * 16) ^ ((lc & 7) << 4)));
#pragma unroll
    for (int dt = 0; dt < 8; dt++) {
#pragma unroll
      for (int ks = 0; ks < 2; ks++) {
        int vrow = dt * 16 + lc;
        bf16x8 vf =
            *(const bf16x8*)(&Vts[vrow * 128 + ((ks * 64 + lg * 16) ^ ((vrow & 7) << 4))]);
        o[dt] = mfma16(af[ks], vf, o[dt]);
      }
    }
    __builtin_amdgcn_s_setprio(0);
  }
  // epilogue: reduce lsum across lg, fetch per-o-row inverse, store bf16
  float rs = lsum;
  rs += __shfl_xor(rs, 16);
  rs += __shfl_xor(rs, 32);
  float inv = 1.0f / rs;
#pragma unroll
  for (int r = 0; r < 4; r++) {
    float invr = __shfl(inv, lg * 4 + r);
    int row = b * 2048 + q0 + w * 16 + lg * 4 + r;
#pragma unroll
    for (int dt = 0; dt < 8; dt++)
      attO[(size_t)row * 2048 + h * 128 + dt * 16 + lc] = (__bf16)(o[dt][r] * invr);
  }
#undef STAGE_KV
}

extern "C" void kernel_launch(void* const* d_in, const int* in_sizes, int n_in,
                              void* d_out, int out_size, void* d_ws, size_t ws_size,
                              hipStream_t stream) {
  const float* X = (const float*)d_in[0];
  const float* Wq = (const float*)d_in[1];
  const float* bq = (const float*)d_in[2];
  const float* Wk = (const float*)d_in[3];
  const float* bk = (const float*)d_in[4];
  const float* Wv = (const float*)d_in[5];
  const float* bv = (const float*)d_in[6];
  const float* Wo = (const float*)d_in[7];
  const float* bo = (const float*)d_in[8];
  char* ws = (char*)d_ws;
  const size_t MB = 1024 * 1024;
  __bf16* Xb  = (__bf16*)(ws + 0);        // 16 MB
  __bf16* WqT = (__bf16*)(ws + 16 * MB);  // 8 MB
  __bf16* WkT = (__bf16*)(ws + 24 * MB);  // 2 MB
  __bf16* WvT = (__bf16*)(ws + 27 * MB);  // 2 MB
  __bf16* WoT = (__bf16*)(ws + 30 * MB);  // 8 MB
  __bf16* Qbf = (__bf16*)(ws + 38 * MB);  // 16 MB
  __bf16* Kp  = (__bf16*)(ws + 54 * MB);  // 4 MB
  __bf16* Vp  = (__bf16*)(ws + 58 * MB);  // 4 MB
  __bf16* Vxt = (__bf16*)(ws + 62 * MB);  // 16 MB
  __bf16* aO  = (__bf16*)(ws + 78 * MB);  // 16 MB -> 94 MB total

  convert_f32_bf16<<<4096, 256, 0, stream>>>(X, Xb);
  transpose_w_bf16<<<dim3(64, 64), 256, 0, stream>>>(Wq, WqT, 2048, 2048);
  transpose_w_bf16<<<dim3(16, 64), 256, 0, stream>>>(Wk, WkT, 2048, 512);
  transpose_w_bf16<<<dim3(16, 64), 256, 0, stream>>>(Wv, WvT, 2048, 512);
  transpose_w_bf16<<<dim3(64, 64), 256, 0, stream>>>(Wo, WoT, 2048, 2048);

  // fold 1/sqrt(HD) * log2(e) into Q so softmax uses exp2 directly
  float qscale = 1.4426950408889634f * 0.08838834764831845f;
  gemm_bt<0><<<dim3(16, 32), 256, 0, stream>>>(Xb, WqT, bq, qscale, Qbf, 4096, 2048, 2048);
  gemm_bt<0><<<dim3(4, 32), 256, 0, stream>>>(Xb, WkT, bk, 1.0f, Kp, 4096, 512, 2048);
  gemm_bt<0><<<dim3(4, 32), 256, 0, stream>>>(Xb, WvT, bv, 1.0f, Vp, 4096, 512, 2048);

  expand_v<<<256, 256, 0, stream>>>(Vp, Vxt);
  attn_fwd<<<dim3(32, 32), 256, 0, stream>>>(Qbf, Kp, Vxt, aO);

  gemm_bt<1><<<dim3(16, 32), 256, 0, stream>>>(aO, WoT, bo, 1.0f, (float*)d_out, 4096, 2048, 2048);
}

// Round 7
// 304.956 us; speedup vs baseline: 2.3083x; 1.3225x over previous
//
#include <hip/hip_runtime.h>

// GQA forward on MI355X. bf16 MFMA everywhere, f32 accum.
// H=16 heads, G=4 groups, D=2048, HD=128, KV=512, bs=2, s=2048.
// Reference's _expand_kv is a RAW RESHAPE:
//   k[b,h,t',d] = Kp[b, h*128 + t'/16, (t'%4)*128 + d]   (same for v)
// => any 128-t' K/V tile = EIGHT 1KB Kp/Vp rows (8KB unique each).
//
// R6 changes (resubmitted R7 verbatim -- R6 bench hit GPU acquisition timeout):
//  - attn: KVBLK=128, V-fold PV: O += Pfold[16q][32] x Vm[32][128d] where
//    Pfold[rr*4+seg] = sum_i P[t'=rr*16+seg+4i]. K A-frag rows permuted
//    (seg=lc>>2) so fold = 3 in-lane adds/nt; Vm k-slots reordered at expand
//    time so af[j]=(bf16)pf[j] lane-local. P LDS buffer GONE. PV MFMAs 4x
//    fewer. K+V dbuf LDS 32KB, counted vmcnt(4), 2 barriers/128-t'.
//  - fused QKV projection gemm (N=3072, grid 24x32) replacing 3 launches.
//  - expand kernel builds only 4MB reordered Vc.

#define DEV __device__ __forceinline__

typedef float f32x4 __attribute__((ext_vector_type(4)));
typedef __bf16 bf16x8 __attribute__((ext_vector_type(8)));

DEV f32x4 mfma16(bf16x8 a, bf16x8 b, f32x4 c) {
  return __builtin_amdgcn_mfma_f32_16x16x32_bf16(a, b, c, 0, 0, 0);
}

// async global->LDS, 16B/lane. LDS dest = wave-uniform base + lane*16;
// global source address is PER-LANE.
DEV void gld16(const void* gsrc, void* ldst) {
  __builtin_amdgcn_global_load_lds(
      (const __attribute__((address_space(1))) unsigned int*)gsrc,
      (__attribute__((address_space(3))) unsigned int*)ldst, 16, 0, 0);
}

// ---------------- X f32 -> bf16 ----------------
__global__ void convert_f32_bf16(const float* __restrict__ in, __bf16* __restrict__ out) {
  size_t i = ((size_t)blockIdx.x * 256 + threadIdx.x) * 8;
  float4 a = *(const float4*)(in + i);
  float4 b = *(const float4*)(in + i + 4);
  bf16x8 v;
  v[0] = (__bf16)a.x; v[1] = (__bf16)a.y; v[2] = (__bf16)a.z; v[3] = (__bf16)a.w;
  v[4] = (__bf16)b.x; v[5] = (__bf16)b.y; v[6] = (__bf16)b.z; v[7] = (__bf16)b.w;
  *(bf16x8*)(out + i) = v;
}

// ---------------- W [K][N] f32 -> WT [N][K] bf16 ----------------
__global__ void transpose_w_bf16(const float* __restrict__ W, __bf16* __restrict__ WT,
                                 int K, int N) {
  __shared__ float t[32][33];
  int tx = threadIdx.x & 31, ty = threadIdx.x >> 5;  // 32x8
  int n0 = blockIdx.x * 32, k0 = blockIdx.y * 32;
#pragma unroll
  for (int i = 0; i < 4; i++)
    t[ty + i * 8][tx] = W[(size_t)(k0 + ty + i * 8) * N + n0 + tx];
  __syncthreads();
#pragma unroll
  for (int i = 0; i < 4; i++)
    WT[(size_t)(n0 + ty + i * 8) * K + k0 + tx] = (__bf16)t[tx][ty + i * 8];
}

// ---------------- generic GEMM (O-proj): C = A * Bt^T + bias ----------------
template <int F32OUT>
__global__ __launch_bounds__(256, 2)
void gemm_bt(const __bf16* __restrict__ A, const __bf16* __restrict__ Bt,
             const float* __restrict__ bias, float scale, void* __restrict__ Cout,
             int M, int N, int K) {
  __shared__ __bf16 As[128 * 32];
  __shared__ __bf16 Bs[128 * 32];
  int tid = threadIdx.x, lane = tid & 63, w = tid >> 6;
  int wm = w >> 1, wn = w & 1, lg = lane >> 4, lc = lane & 15;
  int m0 = blockIdx.y * 128, n0 = blockIdx.x * 128;
  int srow = w * 16 + (lane >> 2), scol = (lane & 3) * 8;
  const __bf16* Ag = A + (size_t)(m0 + srow) * K + scol;
  const __bf16* Bg = Bt + (size_t)(n0 + srow) * K + scol;
  f32x4 acc[4][4] = {};
  int nk = K >> 5;
  for (int kt = 0; kt < nk; ++kt) {
    if (kt) __syncthreads();
    const __bf16* a = Ag + kt * 32;
    const __bf16* bp = Bg + kt * 32;
    gld16((void*)a, As + (w * 16) * 32);
    gld16((void*)(a + (size_t)64 * K), As + (64 + w * 16) * 32);
    gld16((void*)bp, Bs + (w * 16) * 32);
    gld16((void*)(bp + (size_t)64 * K), Bs + (64 + w * 16) * 32);
    __syncthreads();
    bf16x8 af[4], bf[4];
#pragma unroll
    for (int i = 0; i < 4; i++)
      af[i] = *(const bf16x8*)(As + (wm * 64 + i * 16 + lc) * 32 + lg * 8);
#pragma unroll
    for (int i = 0; i < 4; i++)
      bf[i] = *(const bf16x8*)(Bs + (wn * 64 + i * 16 + lc) * 32 + lg * 8);
#pragma unroll
    for (int mi = 0; mi < 4; mi++)
#pragma unroll
      for (int ni = 0; ni < 4; ni++)
        acc[mi][ni] = mfma16(af[mi], bf[ni], acc[mi][ni]);
  }
  float bcol[4];
#pragma unroll
  for (int ni = 0; ni < 4; ni++) bcol[ni] = bias[n0 + wn * 64 + ni * 16 + lc];
#pragma unroll
  for (int mi = 0; mi < 4; mi++)
#pragma unroll
    for (int ni = 0; ni < 4; ni++)
#pragma unroll
      for (int r = 0; r < 4; r++) {
        int row = m0 + wm * 64 + mi * 16 + lg * 4 + r;
        int col = n0 + wn * 64 + ni * 16 + lc;
        float v = (acc[mi][ni][r] + bcol[ni]) * scale;
        if (F32OUT)
          ((float*)Cout)[(size_t)row * N + col] = v;
        else
          ((__bf16*)Cout)[(size_t)row * N + col] = (__bf16)v;
      }
}

// ---------------- fused QKV projection: N=3072 (2048 Q | 512 K | 512 V) ----------------
__global__ __launch_bounds__(256, 2)
void gemm_qkv(const __bf16* __restrict__ A, const __bf16* __restrict__ Bt,
              const float* __restrict__ bq, const float* __restrict__ bk,
              const float* __restrict__ bv, float qscale,
              __bf16* __restrict__ Qo, __bf16* __restrict__ Ko, __bf16* __restrict__ Vo) {
  const int K = 2048;
  __shared__ __bf16 As[128 * 32];
  __shared__ __bf16 Bs[128 * 32];
  int tid = threadIdx.x, lane = tid & 63, w = tid >> 6;
  int wm = w >> 1, wn = w & 1, lg = lane >> 4, lc = lane & 15;
  int m0 = blockIdx.y * 128, n0 = blockIdx.x * 128;
  int srow = w * 16 + (lane >> 2), scol = (lane & 3) * 8;
  const __bf16* Ag = A + (size_t)(m0 + srow) * K + scol;
  const __bf16* Bg = Bt + (size_t)(n0 + srow) * K + scol;
  f32x4 acc[4][4] = {};
  for (int kt = 0; kt < 64; ++kt) {
    if (kt) __syncthreads();
    const __bf16* a = Ag + kt * 32;
    const __bf16* bp = Bg + kt * 32;
    gld16((void*)a, As + (w * 16) * 32);
    gld16((void*)(a + (size_t)64 * K), As + (64 + w * 16) * 32);
    gld16((void*)bp, Bs + (w * 16) * 32);
    gld16((void*)(bp + (size_t)64 * K), Bs + (64 + w * 16) * 32);
    __syncthreads();
    bf16x8 af[4], bf[4];
#pragma unroll
    for (int i = 0; i < 4; i++)
      af[i] = *(const bf16x8*)(As + (wm * 64 + i * 16 + lc) * 32 + lg * 8);
#pragma unroll
    for (int i = 0; i < 4; i++)
      bf[i] = *(const bf16x8*)(Bs + (wn * 64 + i * 16 + lc) * 32 + lg * 8);
#pragma unroll
    for (int mi = 0; mi < 4; mi++)
#pragma unroll
      for (int ni = 0; ni < 4; ni++)
        acc[mi][ni] = mfma16(af[mi], bf[ni], acc[mi][ni]);
  }
  // region select (block-uniform)
  const float* bp;
  __bf16* op;
  int ldc, c0;
  float scl;
  if (n0 < 2048) { bp = bq; op = Qo; ldc = 2048; c0 = n0; scl = qscale; }
  else if (n0 < 2560) { bp = bk; op = Ko; ldc = 512; c0 = n0 - 2048; scl = 1.f; }
  else { bp = bv; op = Vo; ldc = 512; c0 = n0 - 2560; scl = 1.f; }
  float bcol[4];
#pragma unroll
  for (int ni = 0; ni < 4; ni++) bcol[ni] = bp[c0 + wn * 64 + ni * 16 + lc];
#pragma unroll
  for (int mi = 0; mi < 4; mi++)
#pragma unroll
    for (int ni = 0; ni < 4; ni++)
#pragma unroll
      for (int r = 0; r < 4; r++) {
        int row = m0 + wm * 64 + mi * 16 + lg * 4 + r;
        int col = c0 + wn * 64 + ni * 16 + lc;
        op[(size_t)row * ldc + col] = (__bf16)((acc[mi][ni][r] + bcol[ni]) * scl);
      }
}

// ---------------- build reordered+swizzled Vc ----------------
// Vc block (bh, kt128) is 8KB: element (d, kslot) at byte
//   d*64 + ((kslot*2) ^ (((d>>1)&3)<<4)),  value = Vp[b*2048+h*128+kt*8 + (kslot&7)][(kslot>>3)*128 + d]
__global__ void expand_vc(const __bf16* __restrict__ Vp, __bf16* __restrict__ Vc) {
  __shared__ __bf16 Vl[8][512];
  int tid = threadIdx.x;
  int kt = blockIdx.x, bh = blockIdx.y, b = bh >> 4, h = bh & 15;
  size_t base = (size_t)b * 2048 + h * 128 + kt * 8;
#pragma unroll
  for (int i = 0; i < 2; ++i) {
    int idx = i * 256 + tid;  // 512 float4s
    int rr = idx >> 6, ch = idx & 63;
    *(float4*)(&Vl[rr][ch * 8]) = *(const float4*)(Vp + (base + rr) * 512 + ch * 8);
  }
  __syncthreads();
  __bf16* out = Vc + ((size_t)(bh * 16 + kt)) * 4096;
#pragma unroll
  for (int i = 0; i < 2; ++i) {
    int u = i * 256 + tid;  // 512 16B-units
    int d = u >> 2, m = u & 3;
    int seg = m ^ ((d >> 1) & 3);
    bf16x8 val;
#pragma unroll
    for (int j = 0; j < 8; j++) val[j] = Vl[j][seg * 128 + d];
    *(bf16x8*)(out + u * 8) = val;
  }
}

// ---------------- flash attention, causal, fold-PV ----------------
// block = 4 waves, QBLK=64 (16 q/wave), KVBLK=128, LDS 32KB dbuf.
// Q pre-scaled by log2e/sqrt(128); exp2 softmax, swapped QK^T with permuted
// K rows: s[nt][r] = S[t'=nt*16+r*4+lg][q=lc]. Fold in-lane; PV via Vc.
__global__ __launch_bounds__(256, 4)
void attn_fwd(const __bf16* __restrict__ Qb, const __bf16* __restrict__ Kp,
              const __bf16* __restrict__ VcG, __bf16* __restrict__ attO) {
  __shared__ alignas(16) char Kl[2][8192];   // 8 Kp rows, seg-XOR swizzled
  __shared__ alignas(16) char Vld[2][8192];  // Vc block (pre-swizzled in global)
  int tid = threadIdx.x, lane = tid & 63, w = tid >> 6;
  int lg = lane >> 4, lc = lane & 15;
  int qt = 31 - (int)blockIdx.x;  // heavy blocks first
  int bh = blockIdx.y, b = bh >> 4, h = bh & 15;
  int q0 = qt * 64;
  int qg = q0 + w * 16 + lc;
  const __bf16* Qrow = Qb + (size_t)(b * 2048 + qg) * 2048 + h * 128 + lg * 8;
  bf16x8 qf[4];
#pragma unroll
  for (int ks = 0; ks < 4; ks++) qf[ks] = *(const bf16x8*)(Qrow + ks * 32);
  asm volatile("s_waitcnt vmcnt(0)" ::: "memory");  // drain Q loads before counted stages
  f32x4 o[8] = {};
  float mrow = -3.0e38f, lsum = 0.f;  // stats for q=lc (lsum = seg-lg partial)
  const char* KpB = (const char*)Kp + (size_t)(b * 2048 + h * 128) * 1024;  // 1KB rows
  const char* VgB = (const char*)VcG + (size_t)bh * 16 * 8192;
  int ktmax = qt >> 1;
  // K stage: src byte offset within a row carries the seg-XOR (seg = lane>>4)
  int ksw = (lane * 16) ^ ((lane >> 4) << 5);
  // K read: per-lane constants
  int seg = lc >> 2;
  int kro = seg * 256;
  int lg16 = lg * 16;
  int kswr[4];
#pragma unroll
  for (int ks = 0; ks < 4; ks++) kswr[ks] = (ks * 64 + lg16) ^ (seg << 5);
  // V read base (swizzle collapses: (dt*16+lc)&6 == lc&6)
  int vbase = lc * 64 + (lg16 ^ ((lc & 6) << 3));

#define STAGE(bufi, ktile)                                                              \
  do {                                                                                  \
    gld16(KpB + (size_t)((ktile) * 8 + w * 2) * 1024 + ksw, &Kl[bufi][(w * 2) * 1024]); \
    gld16(KpB + (size_t)((ktile) * 8 + w * 2 + 1) * 1024 + ksw,                         \
          &Kl[bufi][(w * 2 + 1) * 1024]);                                               \
    gld16(VgB + (size_t)(ktile) * 8192 + w * 2048 + lane * 16, &Vld[bufi][w * 2048]);   \
    gld16(VgB + (size_t)(ktile) * 8192 + w * 2048 + 1024 + lane * 16,                   \
          &Vld[bufi][w * 2048 + 1024]);                                                 \
  } while (0)

  int cur = 0;
  STAGE(0, 0);
  for (int kt = 0; kt <= ktmax; ++kt) {
    if (kt < ktmax) {
      STAGE(cur ^ 1, kt + 1);
      asm volatile("s_waitcnt vmcnt(4)" ::: "memory");  // this tile landed; next in flight
    } else {
      asm volatile("s_waitcnt vmcnt(0)" ::: "memory");
    }
    __builtin_amdgcn_s_barrier();
    const char* Kc = Kl[cur];
    const char* Vc = Vld[cur];

    // QK^T (swapped, permuted rows): s[nt][r] = S[t'=nt*16+r*4+lg][q=lc]
    f32x4 s[8];
    __builtin_amdgcn_s_setprio(1);
#pragma unroll
    for (int nt = 0; nt < 8; nt++) {
      if (kt * 128 + nt * 16 <= q0 + 63) {  // block-uniform liveness
        s[nt] = (f32x4){0.f, 0.f, 0.f, 0.f};
#pragma unroll
        for (int ks = 0; ks < 4; ks++) {
          bf16x8 kf = *(const bf16x8*)(Kc + nt * 1024 + kro + kswr[ks]);
          s[nt] = mfma16(kf, qf[ks], s[nt]);
        }
      } else {
        s[nt] = (f32x4){-3.0e38f, -3.0e38f, -3.0e38f, -3.0e38f};
      }
    }
    __builtin_amdgcn_s_setprio(0);
    if (kt == ktmax) {  // causal mask on diagonal 128-block
#pragma unroll
      for (int nt = 0; nt < 8; nt++)
#pragma unroll
        for (int r = 0; r < 4; r++)
          if (kt * 128 + nt * 16 + r * 4 + lg > qg) s[nt][r] = -3.0e38f;
    }
    // row max over all 128 t' for q=lc: in-lane 31 fmax + xor16/32
    float v = fmaxf(fmaxf(s[0][0], s[0][1]), fmaxf(s[0][2], s[0][3]));
#pragma unroll
    for (int nt = 1; nt < 8; nt++)
      v = fmaxf(v, fmaxf(fmaxf(s[nt][0], s[nt][1]), fmaxf(s[nt][2], s[nt][3])));
    v = fmaxf(v, __shfl_xor(v, 16));
    v = fmaxf(v, __shfl_xor(v, 32));
    if (__any(v > mrow + 8.0f)) {  // defer-max rescale (rare after first tile)
      float mn = fmaxf(mrow, v);
      float sc = exp2f(mrow - mn);
      mrow = mn;
      lsum *= sc;
#pragma unroll
      for (int r = 0; r < 4; r++) {
        float scr = __shfl(sc, lg * 4 + r);
#pragma unroll
        for (int dt = 0; dt < 8; dt++) o[dt][r] *= scr;
      }
    }
    // exp2 + in-lane fold: pf[nt] = Pfold[q=lc][k32 = nt*4 + lg]
    float pf[8];
    float rs = 0.f;
#pragma unroll
    for (int nt = 0; nt < 8; nt++) {
      float e0 = exp2f(s[nt][0] - mrow);
      float e1 = exp2f(s[nt][1] - mrow);
      float e2 = exp2f(s[nt][2] - mrow);
      float e3 = exp2f(s[nt][3] - mrow);
      pf[nt] = (e0 + e1) + (e2 + e3);
      rs += pf[nt];
    }
    lsum += rs;  // partial (this lane's lg-slice); reduced in epilogue
    bf16x8 af;
#pragma unroll
    for (int j = 0; j < 8; j++) af[j] = (__bf16)pf[j];
    // PV: o[16q][128d] += Pfold * Vm  (8 MFMAs, zero cross-lane)
    __builtin_amdgcn_s_setprio(1);
#pragma unroll
    for (int dt = 0; dt < 8; dt++) {
      bf16x8 vf = *(const bf16x8*)(Vc + dt * 1024 + vbase);
      o[dt] = mfma16(af, vf, o[dt]);
    }
    __builtin_amdgcn_s_setprio(0);
    __builtin_amdgcn_s_barrier();  // all waves done with buf[cur] before overwrite
    cur ^= 1;
  }
  // epilogue: reduce lg-partial row sums, divide, store bf16
  lsum += __shfl_xor(lsum, 16);
  lsum += __shfl_xor(lsum, 32);
  float inv = 1.0f / lsum;
#pragma unroll
  for (int r = 0; r < 4; r++) {
    float invr = __shfl(inv, lg * 4 + r);
    int row = b * 2048 + q0 + w * 16 + lg * 4 + r;
#pragma unroll
    for (int dt = 0; dt < 8; dt++)
      attO[(size_t)row * 2048 + h * 128 + dt * 16 + lc] = (__bf16)(o[dt][r] * invr);
  }
#undef STAGE
}

extern "C" void kernel_launch(void* const* d_in, const int* in_sizes, int n_in,
                              void* d_out, int out_size, void* d_ws, size_t ws_size,
                              hipStream_t stream) {
  const float* X = (const float*)d_in[0];
  const float* Wq = (const float*)d_in[1];
  const float* bq = (const float*)d_in[2];
  const float* Wk = (const float*)d_in[3];
  const float* bk = (const float*)d_in[4];
  const float* Wv = (const float*)d_in[5];
  const float* bv = (const float*)d_in[6];
  const float* Wo = (const float*)d_in[7];
  const float* bo = (const float*)d_in[8];
  char* ws = (char*)d_ws;
  const size_t MB = 1024 * 1024;
  __bf16* Xb     = (__bf16*)(ws + 0);        // 16 MB
  __bf16* WqkvT  = (__bf16*)(ws + 16 * MB);  // 12 MB (3072 x 2048)
  __bf16* WoT    = (__bf16*)(ws + 28 * MB);  // 8 MB
  __bf16* Qbf    = (__bf16*)(ws + 36 * MB);  // 16 MB
  __bf16* Kp     = (__bf16*)(ws + 52 * MB);  // 4 MB
  __bf16* Vp     = (__bf16*)(ws + 56 * MB);  // 4 MB
  __bf16* Vc     = (__bf16*)(ws + 60 * MB);  // 4 MB (reordered V)
  __bf16* aO     = (__bf16*)(ws + 64 * MB);  // 16 MB -> 80 MB total

  convert_f32_bf16<<<4096, 256, 0, stream>>>(X, Xb);
  transpose_w_bf16<<<dim3(64, 64), 256, 0, stream>>>(Wq, WqkvT, 2048, 2048);
  transpose_w_bf16<<<dim3(16, 64), 256, 0, stream>>>(Wk, WqkvT + (size_t)2048 * 2048, 2048, 512);
  transpose_w_bf16<<<dim3(16, 64), 256, 0, stream>>>(Wv, WqkvT + (size_t)2560 * 2048, 2048, 512);
  transpose_w_bf16<<<dim3(64, 64), 256, 0, stream>>>(Wo, WoT, 2048, 2048);

  // fold 1/sqrt(HD) * log2(e) into Q so softmax uses exp2 directly
  float qscale = 1.4426950408889634f * 0.08838834764831845f;
  gemm_qkv<<<dim3(24, 32), 256, 0, stream>>>(Xb, WqkvT, bq, bk, bv, qscale, Qbf, Kp, Vp);

  expand_vc<<<dim3(16, 32), 256, 0, stream>>>(Vp, Vc);
  attn_fwd<<<dim3(32, 32), 256, 0, stream>>>(Qbf, Kp, Vc, aO);

  gemm_bt<1><<<dim3(16, 32), 256, 0, stream>>>(aO, WoT, bo, 1.0f, (float*)d_out, 4096, 2048, 2048);
}